// Round 3
// baseline (630.327 us; speedup 1.0000x reference)
//
#include <hip/hip_runtime.h>
#include <stdint.h>

// B=131072 rows, K=IN=256, N=OUT=256.
// temp = act @ weight.T (exact int32, |t| < 2^23); r = max|temp|;
// bw = ceil(log2(max(r,1))) (0 if r<=1); shift = bw-7;
// shift>0 ? round_shift(temp,shift) clipped to [-127,127] : int8-wrap(temp)
// exp_out = exp_in + weight_exp + max(shift,0)  (int16 semantics)
// Harness reads d_out as INT32: [B*N values, 1 exp scalar].
//
// v4: v3 structure with the spill fixed.
//  - v3 post-mortem: araw[16] (64 VGPR) + acc[16] (64 VGPR) > 128-VGPR cap
//    -> A-strip spilled to scratch (+134 MB fetch, +134 MB write, 299 us).
//  - Fix: rolling depth-2 K-chunk prefetch (16 VGPR of raw A live, not 64),
//    1024-thread blocks @ __launch_bounds__(1024,4) -> 16 waves/CU at
//    <=128 VGPR/wave. Barrier-free steady state kept; B in LDS once/block.

#define M_ROWS 131072
#define NK 256
#define BLK_ROWS 512
#define BST 264      // padded LDS row stride (bf16 elems) = 528 B

typedef __attribute__((ext_vector_type(8))) short bf16x8;
typedef __attribute__((ext_vector_type(4))) float f32x4;
typedef __attribute__((ext_vector_type(4))) float fv4;
typedef __attribute__((ext_vector_type(4))) int iv4;
typedef __attribute__((ext_vector_type(4))) unsigned int u32x4;
typedef __attribute__((ext_vector_type(4))) unsigned short us4;

// bf16(lo) in low 16 bits, bf16(hi) in high 16 bits -- one v_perm_b32.
// exact for integer-valued floats |v| <= 255.
__device__ __forceinline__ uint32_t pack2(float lo, float hi) {
  return __builtin_amdgcn_perm(__float_as_uint(hi), __float_as_uint(lo),
                               0x07060302u);
}

// Prepass: weight fp32 -> bf16 (65536 elems; L2/LLC-resident, 128 KB).
// Also zero-inits gmax (replaces a separate memset dispatch).
__global__ void wconv(const float* __restrict__ w, unsigned short* __restrict__ wb,
                      int* __restrict__ gmax) {
  if (blockIdx.x == 0 && threadIdx.x == 0) *gmax = 0;
  const int i = blockIdx.x * 256 + threadIdx.x;
  const fv4 f = ((const fv4*)w)[i];
  us4 o;
  o.x = (unsigned short)(__float_as_uint(f.x) >> 16);
  o.y = (unsigned short)(__float_as_uint(f.y) >> 16);
  o.z = (unsigned short)(__float_as_uint(f.z) >> 16);
  o.w = (unsigned short)(__float_as_uint(f.w) >> 16);
  ((us4*)wb)[i] = o;
}

// pass 1: streaming GEMM -> raw int32 store + global abs-max.
__global__ __launch_bounds__(1024, 4) void gemm_maxstore(
    const float* __restrict__ act, const unsigned short* __restrict__ wgtb,
    int* __restrict__ out, int* __restrict__ gmax)
{
  __shared__ __align__(16) short Bs[NK * BST];   // 132 KB -> 1 block/CU
  __shared__ int smax;
  const int tid = threadIdx.x;
  if (tid == 0) smax = 0;

  // Stage full B once: wb row-major [col][k] bf16 -> padded LDS.
  for (int v = tid; v < NK * NK / 8; v += 1024) {
    const int col = v >> 5;           // 8 shorts per vec, 32 vecs per row
    const int k   = (v & 31) << 3;
    *(u32x4*)&Bs[col * BST + k] = ((const u32x4*)wgtb)[v];
  }
  __syncthreads();   // the only barrier before the epilogue

  const int lane = tid & 63;
  const int wave = tid >> 6;          // 16 waves
  const int lm   = lane & 15;
  const int lk   = lane >> 4;
  const int bm   = blockIdx.x * BLK_ROWS;

  float fmaxv = 0.0f;

#pragma unroll 1
  for (int s = wave; s < BLK_ROWS / 16; s += 16) {   // 2 strips per wave
    const int row0 = bm + s * 16;
    const float* arow = act + (size_t)(row0 + lm) * NK + lk * 8;

    // Rolling depth-2 prefetch of 32-element K-chunks (2 fv4 per chunk).
    fv4 p0a = *(const fv4*)(arow);
    fv4 p0b = *(const fv4*)(arow + 4);
    fv4 p1a = *(const fv4*)(arow + 32);
    fv4 p1b = *(const fv4*)(arow + 36);

    f32x4 acc[16] = {};
#pragma unroll
    for (int kk = 0; kk < 8; ++kk) {
      const fv4 ca = (kk & 1) ? p1a : p0a;    // static under full unroll
      const fv4 cb = (kk & 1) ? p1b : p0b;
      u32x4 apk;
      apk.x = pack2(ca.x, ca.y);
      apk.y = pack2(ca.z, ca.w);
      apk.z = pack2(cb.x, cb.y);
      apk.w = pack2(cb.z, cb.w);
      if (kk + 2 < 8) {                       // prefetch chunk kk+2
        if (kk & 1) {
          p1a = *(const fv4*)(arow + (kk + 2) * 32);
          p1b = *(const fv4*)(arow + (kk + 2) * 32 + 4);
        } else {
          p0a = *(const fv4*)(arow + (kk + 2) * 32);
          p0b = *(const fv4*)(arow + (kk + 2) * 32 + 4);
        }
      }
      const bf16x8 af = __builtin_bit_cast(bf16x8, apk);
#pragma unroll
      for (int ni = 0; ni < 16; ++ni) {
        const bf16x8 bfr =
            *(const bf16x8*)&Bs[(ni * 16 + lm) * BST + kk * 32 + lk * 8];
        acc[ni] = __builtin_amdgcn_mfma_f32_16x16x32_bf16(af, bfr, acc[ni],
                                                          0, 0, 0);
      }
    }

    // Epilogue: abs-max + raw int32 store (cached -> LLC for pass 2).
    const size_t obase = (size_t)(row0 + lk * 4) * NK + lm;
#pragma unroll
    for (int ni = 0; ni < 16; ++ni)
#pragma unroll
      for (int r = 0; r < 4; ++r) {
        const float tv = acc[ni][r];
        fmaxv = fmaxf(fmaxv, fabsf(tv));
        out[obase + (size_t)r * NK + ni * 16] = (int)tv;
      }
  }

#pragma unroll
  for (int off = 32; off; off >>= 1)
    fmaxv = fmaxf(fmaxv, __shfl_xor(fmaxv, off, 64));
  if (lane == 0) atomicMax(&smax, (int)fmaxv);
  __syncthreads();
  if (tid == 0) atomicMax(gmax, smax);
}

// pass 2: in-place elementwise quantize of d_out (raw temp is LLC-hot).
__global__ __launch_bounds__(256) void quant_pass(
    int* __restrict__ out, const int* __restrict__ gmax,
    const int* __restrict__ exp_in, const int* __restrict__ wexp)
{
  const int rmax = *gmax;
  const int bw = (rmax <= 1) ? 0 : (32 - __clz(rmax - 1));   // ceil(log2(r))
  const int shift = bw - 7;
  const bool pos = shift > 0;
  const int s = shift < 1 ? 1 : shift;

  const size_t total  = (size_t)M_ROWS * NK / 4;  // int4 vectors
  const size_t stride = (size_t)gridDim.x * blockDim.x;
  for (size_t i = (size_t)blockIdx.x * blockDim.x + threadIdx.x; i < total;
       i += stride) {
    iv4 t = ((const iv4*)out)[i];
    iv4 q;
#pragma unroll
    for (int j = 0; j < 4; ++j) {
      const int ti = t[j];
      int r;
      if (pos) {
        const int rt = ti >> s;                       // floor(t / 2^s)
        const int dec = (ti - (rt << s)) >> (s - 1);  // {0,1}
        r = rt + dec;
        r = r > 127 ? 127 : (r < -127 ? -127 : r);
      } else {
        r = (int)(signed char)(ti & 0xFF);            // int8 wrap
      }
      q[j] = r;
    }
    __builtin_nontemporal_store(q, &((iv4*)out)[i]); // final, never re-read
  }

  if (blockIdx.x == 0 && threadIdx.x == 0) {
    const int e = exp_in[0] + wexp[0] + (pos ? shift : 0);
    out[(size_t)M_ROWS * NK] = (int)(short)e;
  }
}

extern "C" void kernel_launch(void* const* d_in, const int* in_sizes, int n_in,
                              void* d_out, int out_size, void* d_ws, size_t ws_size,
                              hipStream_t stream) {
  const float* act   = (const float*)d_in[0];
  const int* exp_in  = (const int*)d_in[1];
  const float* wgt   = (const float*)d_in[2];
  const int* wexp    = (const int*)d_in[3];
  int* gmax          = (int*)d_ws;
  unsigned short* wb = (unsigned short*)((char*)d_ws + 128);  // 128 KB bf16 weight

  wconv<<<dim3(64), dim3(256), 0, stream>>>(wgt, wb, gmax);
  gemm_maxstore<<<dim3(M_ROWS / BLK_ROWS), dim3(1024), 0, stream>>>(
      act, wb, (int*)d_out, gmax);
  quant_pass<<<dim3(2048), dim3(256), 0, stream>>>((int*)d_out, gmax, exp_in, wexp);
}

// Round 4
// 285.796 us; speedup vs baseline: 2.2055x; 2.2055x over previous
//
#include <hip/hip_runtime.h>
#include <stdint.h>

// B=131072 rows, K=IN=256, N=OUT=256.
// temp = act @ weight.T (exact int32, |t| < 2^23); r = max|temp|;
// bw = ceil(log2(max(r,1))) (0 if r<=1); shift = bw-7;
// shift>0 ? round_shift(temp,shift) clipped to [-127,127] : int8-wrap(temp)
// exp_out = exp_in + weight_exp + max(shift,0)  (int16 semantics)
// Harness reads d_out as INT32: [B*N values, 1 exp scalar].
//
// v5: revert to the PROVEN v2 structure (84 us, VGPR 84, zero spill) and
// scale the block: BM 64->128, 512 threads (8 waves, 2x4 wave grid).
//  - per-wave decomposition unchanged (acc[4][4] 64x64 sub-tile) -- the
//    v3/v4 acc[16] strip decomposition spilled (574/639 MB scratch traffic).
//  - 55 KB LDS -> 2 blocks/CU -> 16 waves/CU (50% occ, 2x v2's hiding).
//  - B staged per 128 rows instead of per 64 -> half the L2->LDS B traffic,
//    half the barriers per output element.
// pass 2 unchanged: in-place elementwise quantize (raw temp LLC-resident).

#define M_ROWS 131072
#define NK 256
#define BM 128
#define BK 64
#define BKP 72      // padded LDS row stride (bf16 elems) = 144 B

typedef __attribute__((ext_vector_type(8))) short bf16x8;
typedef __attribute__((ext_vector_type(4))) float f32x4;
typedef __attribute__((ext_vector_type(4))) float fv4;
typedef __attribute__((ext_vector_type(4))) int iv4;
typedef __attribute__((ext_vector_type(4))) unsigned int u32x4;
typedef __attribute__((ext_vector_type(4))) unsigned short us4;

__device__ __forceinline__ uint32_t pack_bf16(float a, float b) {
  // exact for integer-valued floats |v| <= 255 (single v_perm_b32)
  return __builtin_amdgcn_perm(__float_as_uint(b), __float_as_uint(a),
                               0x07060302u);
}

// Prepass: weight fp32 -> bf16 (65536 elems; L2/LLC-resident, 128 KB).
// Also zero-inits gmax (replaces a separate memset dispatch).
__global__ void wconv(const float* __restrict__ w, unsigned short* __restrict__ wb,
                      int* __restrict__ gmax) {
  if (blockIdx.x == 0 && threadIdx.x == 0) *gmax = 0;
  const int i = blockIdx.x * 256 + threadIdx.x;
  const fv4 f = ((const fv4*)w)[i];
  us4 o;
  o.x = (unsigned short)(__float_as_uint(f.x) >> 16);
  o.y = (unsigned short)(__float_as_uint(f.y) >> 16);
  o.z = (unsigned short)(__float_as_uint(f.z) >> 16);
  o.w = (unsigned short)(__float_as_uint(f.w) >> 16);
  ((us4*)wb)[i] = o;
}

// pass 1: GEMM -> raw int32 store (cached: LLC feeds pass 2) + global abs-max.
// 512 threads = 8 waves in a 2x4 grid; wave (wr,wc) owns rows wr*64..+63,
// cols wc*64..+63 of the 128x256 block tile.
__global__ __launch_bounds__(512, 2) void gemm_maxstore(
    const float* __restrict__ act, const unsigned short* __restrict__ wgtb,
    int* __restrict__ out, int* __restrict__ gmax)
{
  __shared__ __align__(16) short As[BM * BKP];   // 18432 B
  __shared__ __align__(16) short Bs[NK * BKP];   // 36864 B  (total ~55 KB)
  __shared__ int smax;
  const int tid = threadIdx.x;
  if (tid == 0) smax = 0;

  const int bm   = blockIdx.x * BM;
  const int lane = tid & 63;
  const int wave = tid >> 6;      // 0..7
  const int wr   = wave >> 2;     // 0..1  (row half)
  const int wc   = wave & 3;      // 0..3  (col quarter)
  const int lm   = lane & 15;
  const int lk   = lane >> 4;

  // Staging roles: 512 threads; A = 128 rows x 64 k (2 rows/thread),
  // B = 256 cols x 64 k (4 cols/thread); 8 bf16 (one u32x4) per chunk.
  const int arow = tid >> 3;          // 0..63 (+64 for j=1)
  const int aks  = (tid & 7) * 8;
  const int brow = tid >> 3;          // 0..63 (+64*j, j<4)
  const int bks  = (tid & 7) * 8;

  uint32_t apk[2][4];
  u32x4 breg[4];

#pragma unroll
  for (int j = 0; j < 2; ++j) {
    const float* p = act + (size_t)(bm + arow + j * 64) * NK + aks;
    const fv4 f0 = *(const fv4*)p;
    const fv4 f1 = *((const fv4*)p + 1);
    apk[j][0] = pack_bf16(f0.x, f0.y); apk[j][1] = pack_bf16(f0.z, f0.w);
    apk[j][2] = pack_bf16(f1.x, f1.y); apk[j][3] = pack_bf16(f1.z, f1.w);
  }
#pragma unroll
  for (int j = 0; j < 4; ++j)
    breg[j] = *(const u32x4*)(wgtb + (size_t)(brow + j * 64) * NK + bks);

  f32x4 acc[4][4] = {};

  for (int kt = 0; kt < NK; kt += BK) {
    __syncthreads();
#pragma unroll
    for (int j = 0; j < 2; ++j)
      *(u32x4*)&As[(arow + j * 64) * BKP + aks] = *(const u32x4*)apk[j];
#pragma unroll
    for (int j = 0; j < 4; ++j)
      *(u32x4*)&Bs[(brow + j * 64) * BKP + bks] = breg[j];
    __syncthreads();

    if (kt + BK < NK) {
      const int ktn = kt + BK;
#pragma unroll
      for (int j = 0; j < 2; ++j) {
        const float* p = act + (size_t)(bm + arow + j * 64) * NK + ktn + aks;
        const fv4 f0 = *(const fv4*)p;
        const fv4 f1 = *((const fv4*)p + 1);
        apk[j][0] = pack_bf16(f0.x, f0.y); apk[j][1] = pack_bf16(f0.z, f0.w);
        apk[j][2] = pack_bf16(f1.x, f1.y); apk[j][3] = pack_bf16(f1.z, f1.w);
      }
#pragma unroll
      for (int j = 0; j < 4; ++j)
        breg[j] = *(const u32x4*)(wgtb + (size_t)(brow + j * 64) * NK + ktn + bks);
    }

#pragma unroll
    for (int kk = 0; kk < BK; kk += 32) {
      bf16x8 af[4], bfr[4];
#pragma unroll
      for (int mi = 0; mi < 4; ++mi)
        af[mi] = *(const bf16x8*)&As[(wr * 64 + mi * 16 + lm) * BKP + kk + lk * 8];
#pragma unroll
      for (int ni = 0; ni < 4; ++ni)
        bfr[ni] = *(const bf16x8*)&Bs[(wc * 64 + ni * 16 + lm) * BKP + kk + lk * 8];
#pragma unroll
      for (int mi = 0; mi < 4; ++mi)
#pragma unroll
        for (int ni = 0; ni < 4; ++ni)
          acc[mi][ni] = __builtin_amdgcn_mfma_f32_16x16x32_bf16(
              af[mi], bfr[ni], acc[mi][ni], 0, 0, 0);
    }
  }

  // Epilogue: abs-max + raw int32 store.
  int imax = 0;
#pragma unroll
  for (int mi = 0; mi < 4; ++mi)
#pragma unroll
    for (int ni = 0; ni < 4; ++ni)
#pragma unroll
      for (int r = 0; r < 4; ++r) {
        const int ti = (int)acc[mi][ni][r];
        const int a = ti < 0 ? -ti : ti;
        imax = a > imax ? a : imax;
        const int m = bm + wr * 64 + mi * 16 + lk * 4 + r;
        const int n = wc * 64 + ni * 16 + lm;
        out[(size_t)m * NK + n] = ti;   // cached store -> LLC for pass 2
      }
#pragma unroll
  for (int off = 32; off; off >>= 1) {
    const int o = __shfl_xor(imax, off, 64);
    imax = o > imax ? o : imax;
  }
  if (lane == 0) atomicMax(&smax, imax);
  __syncthreads();
  if (tid == 0) atomicMax(gmax, smax);
}

// pass 2: in-place elementwise quantize of d_out (raw temp is LLC-hot).
__global__ __launch_bounds__(256) void quant_pass(
    int* __restrict__ out, const int* __restrict__ gmax,
    const int* __restrict__ exp_in, const int* __restrict__ wexp)
{
  const int rmax = *gmax;
  const int bw = (rmax <= 1) ? 0 : (32 - __clz(rmax - 1));   // ceil(log2(r))
  const int shift = bw - 7;
  const bool pos = shift > 0;
  const int s = shift < 1 ? 1 : shift;

  const size_t total  = (size_t)M_ROWS * NK / 4;  // int4 vectors
  const size_t stride = (size_t)gridDim.x * blockDim.x;
  for (size_t i = (size_t)blockIdx.x * blockDim.x + threadIdx.x; i < total;
       i += stride) {
    iv4 t = ((const iv4*)out)[i];
    iv4 q;
#pragma unroll
    for (int j = 0; j < 4; ++j) {
      const int ti = t[j];
      int r;
      if (pos) {
        const int rt = ti >> s;                       // floor(t / 2^s)
        const int dec = (ti - (rt << s)) >> (s - 1);  // {0,1}
        r = rt + dec;
        r = r > 127 ? 127 : (r < -127 ? -127 : r);
      } else {
        r = (int)(signed char)(ti & 0xFF);            // int8 wrap
      }
      q[j] = r;
    }
    __builtin_nontemporal_store(q, &((iv4*)out)[i]); // final, never re-read
  }

  if (blockIdx.x == 0 && threadIdx.x == 0) {
    const int e = exp_in[0] + wexp[0] + (pos ? shift : 0);
    out[(size_t)M_ROWS * NK] = (int)(short)e;
  }
}

extern "C" void kernel_launch(void* const* d_in, const int* in_sizes, int n_in,
                              void* d_out, int out_size, void* d_ws, size_t ws_size,
                              hipStream_t stream) {
  const float* act   = (const float*)d_in[0];
  const int* exp_in  = (const int*)d_in[1];
  const float* wgt   = (const float*)d_in[2];
  const int* wexp    = (const int*)d_in[3];
  int* gmax          = (int*)d_ws;
  unsigned short* wb = (unsigned short*)((char*)d_ws + 128);  // 128 KB bf16 weight

  wconv<<<dim3(64), dim3(256), 0, stream>>>(wgt, wb, gmax);
  gemm_maxstore<<<dim3(M_ROWS / BM), dim3(512), 0, stream>>>(act, wb, (int*)d_out,
                                                             gmax);
  quant_pass<<<dim3(2048), dim3(256), 0, stream>>>((int*)d_out, gmax, exp_in, wexp);
}